// Round 7
// baseline (14.591 us; speedup 1.0000x reference)
//
#include <hip/hip_runtime.h>

#define BB 8
#define LZ 1024
#define LL 1024
#define HH 1024
#define W  16     // Gaussian band: weight at |d|=8 is exp(-32) ~ 1e-14, far below thr
#define TL 8      // output rows per block
#define CUMAX 32  // union window: W + ceil(7 * max_slope(=2)) + pad = 16+14+2

typedef float vfloat4 __attribute__((ext_vector_type(4)));

// Diagonal supertile->XCD mapping: supertile s (16 tiles = 128 l-rows) of batch
// b runs on XCD (b+s)&7 (blockIdx round-robins across XCDs). Each XCD gets one
// supertile of each index from 8 different batches -> work ~768 rows/XCD
// (balanced), and a ~4MB contiguous z footprint (L2-resident).
__global__ __launch_bounds__(256) void lenconv_kernel(
    const float* __restrict__ z,
    const int* __restrict__ ls,
    const float* __restrict__ z_mask,
    const float* __restrict__ sigma,
    float* __restrict__ out,        // z_prime [B, LL, HH]
    float* __restrict__ out_mask)   // zp_mask [B, LL]
{
    int B = blockIdx.x;
    int x = B & 7;          // target XCD
    int j = B >> 3;         // 0..127 within XCD
    int s = j >> 4;         // supertile index 0..7
    int i = j & 15;         // tile within supertile
    int b = (x - s) & 7;    // batch owning this supertile
    int l0 = (s * 16 + i) * TL;
    int t = threadIdx.x;

    int lsb = ls[b];

    vfloat4* o4 = reinterpret_cast<vfloat4*>(out + ((size_t)b * LL + l0) * HH);

    if (t < TL) out_mask[(size_t)b * LL + l0 + t] = ((l0 + t) < lsb) ? 1.f : 0.f;

    // ---- fully-invalid tile: write zeros (NT) and exit. Block-uniform branch. ----
    if (l0 >= lsb) {
        vfloat4 zero = {0.f, 0.f, 0.f, 0.f};
        #pragma unroll
        for (int i2 = 0; i2 < TL; ++i2)
            __builtin_nontemporal_store(zero, &o4[(size_t)i2 * (HH / 4) + t]);
        return;
    }

    __shared__ float smask[LZ];
    __shared__ float wd[TL][CUMAX];
    __shared__ float red[4];

    // ---- 1) z_mask row -> LDS, and n = sum(z_mask[b,:]) ----
    const vfloat4* zm4 = reinterpret_cast<const vfloat4*>(z_mask + (size_t)b * LZ);
    vfloat4 m4 = zm4[t];
    reinterpret_cast<vfloat4*>(smask)[t] = m4;
    float sred = m4.x + m4.y + m4.z + m4.w;
    #pragma unroll
    for (int off = 32; off > 0; off >>= 1) sred += __shfl_xor(sred, off, 64);
    if ((t & 63) == 0) red[t >> 6] = sred;

    // zero dense weight table (written before the same barrier)
    for (int q = t; q < TL * CUMAX; q += 256) ((float*)wd)[q] = 0.f;
    __syncthreads();

    float n   = red[0] + red[1] + red[2] + red[3];
    float slope = n / (float)lsb;
    float sg  = sigma[0];
    float inv2s2 = 0.5f / (sg * sg);

    // union window from rows 0 and TL-1 (c0 monotone in l)
    float mu0 = (float)l0 * slope;
    int cu0 = min(max((int)floorf(mu0 + 0.5f) - W / 2, 0), LZ - W);
    float muL = (float)(l0 + TL - 1) * slope;
    int cuE = min(max((int)floorf(muL + 0.5f) - W / 2, 0), LZ - W) + W;
    int CU = cuE - cu0;      // <= CUMAX

    // ---- 2) per-row band softmax: 16-lane group per row, threads 0..127 ----
    if (t < TL * W) {
        int r = t >> 4;          // row within tile (0..7)
        int k = t & 15;          // tap within band
        int l = l0 + r;
        float mu = (float)l * slope;
        int c0 = (int)floorf(mu + 0.5f) - W / 2;
        c0 = min(max(c0, 0), LZ - W);

        float zm = smask[c0 + k];
        float d  = (float)(c0 + k) - mu;
        float lg = -(d * d) * inv2s2 * zm - 99.f * (1.f - zm);
        float mx = lg;
        #pragma unroll
        for (int off = 8; off > 0; off >>= 1) mx = fmaxf(mx, __shfl_xor(mx, off, 64));
        float e = __expf(lg - mx);
        float ssum = e;
        #pragma unroll
        for (int off = 8; off > 0; off >>= 1) ssum += __shfl_xor(ssum, off, 64);
        if (l < lsb) wd[r][(c0 - cu0) + k] = e / ssum;   // invalid rows stay all-zero
    }
    __syncthreads();

    // ---- 3) banded accumulate: each thread owns 4 H-columns x TL rows ----
    const vfloat4* z4 = reinterpret_cast<const vfloat4*>(z + ((size_t)b * LZ + cu0) * HH);
    vfloat4 acc[TL];
    #pragma unroll
    for (int q = 0; q < TL; ++q) acc[q] = (vfloat4){0.f, 0.f, 0.f, 0.f};

    #pragma unroll 4
    for (int c = 0; c < CU; ++c) {
        vfloat4 v = z4[(size_t)c * (HH / 4) + t];
        #pragma unroll
        for (int q = 0; q < TL; ++q) {
            float w = wd[q][c];    // uniform address -> LDS broadcast
            acc[q] += w * v;
        }
    }

    #pragma unroll
    for (int q = 0; q < TL; ++q)
        __builtin_nontemporal_store(acc[q], &o4[(size_t)q * (HH / 4) + t]);
}

extern "C" void kernel_launch(void* const* d_in, const int* in_sizes, int n_in,
                              void* d_out, int out_size, void* d_ws, size_t ws_size,
                              hipStream_t stream) {
    const float* z      = (const float*)d_in[0];
    const int*   ls     = (const int*)d_in[1];
    const float* z_mask = (const float*)d_in[2];
    const float* sigma  = (const float*)d_in[3];

    float* out      = (float*)d_out;
    float* out_mask = out + (size_t)BB * LL * HH;

    lenconv_kernel<<<BB * (LL / TL), 256, 0, stream>>>(z, ls, z_mask, sigma, out, out_mask);
}